// Round 3
// baseline (157.745 us; speedup 1.0000x reference)
//
#include <hip/hip_runtime.h>

#define B_ 2
#define C_ 256
#define H_ 56
#define W_ 56
#define N_ 64
#define M_ 8
#define P_ 7
#define Y2_ (H_/2)               // 28 y-row pairs
#define Y4_ (H_/4)               // 14 y-row quads
#define JR_ (1 + M_)             // 9 rois per (b,n): box + 8 full ctx unions
#define WROW_ 8                  // padded weight-row stride (7 used + col7 = 0)

typedef _Float16 half2v __attribute__((ext_vector_type(2)));

#if __has_builtin(__builtin_amdgcn_fdot2)
#define FDOT2(a, b, c) __builtin_amdgcn_fdot2((a), (b), (c), false)
#else
static __device__ __forceinline__ float FDOT2(half2v a, half2v b, float c) {
    return fmaf((float)a.x, (float)b.x, fmaf((float)a.y, (float)b.y, c));
}
#endif

// ---- workspace layout (dword-element offsets) ----
#define F_FMT4 0
#define N_FMT4 (B_*Y4_*W_*C_*2)              // 802,816 dw  f16 y-QUAD-packed fmap
#define F_OUTS (F_FMT4 + N_FMT4)
#define N_OUTS (B_*N_*49*C_)                 // 1,605,632 staging out [b][n][py][px][c]
#define WS_ELEMS (F_OUTS + N_OUTS)

// prep kernel: transpose only (outS zeroing moved to hipMemsetAsync)
#define PREP_T (B_*Y4_*4*2)                  // 224: (b, y4, cgroup, xhalf) transpose

// ---------------------------------------------------------------------------
// k_prep: COALESCED fm -> fmt4 via LDS tile (R2-verified).
//   phase 1 reads fm rows contiguously (112B runs), phase 2 packs half2
//   quads and stores c-contiguous (512B/wave).
__global__ __launch_bounds__(256) void k_prep(const float* __restrict__ fm,
                                              float* __restrict__ ws_f) {
    __shared__ float t[28 * 257 + 8];        // [x28][y4][c64], x-stride 257 pad
    int bid = blockIdx.x;
    int tid = (int)threadIdx.x;

    int xh = bid & 1;
    int cg = (bid >> 1) & 3;
    int y4 = (bid >> 3) % Y4_;
    int b  = (bid >> 3) / Y4_;
    int c0 = cg * 64, x0 = xh * 28;
    for (int e = tid; e < 64 * 4 * 28; e += 256) {
        int c_l = e / 112, rem = e % 112;
        int y_l = rem / 28, x_l = rem % 28;
        t[x_l * 257 + y_l * 64 + c_l] =
            fm[(((size_t)b * C_ + c0 + c_l) * H_ + 4 * y4 + y_l) * W_ + x0 + x_l];
    }
    __syncthreads();
    uint2* dst = (uint2*)ws_f;
    for (int e = tid; e < 28 * 64; e += 256) {
        int x_l = e >> 6, c_l = e & 63;
        const float* p = &t[x_l * 257 + c_l];
        half2v lo, hi; uint2 o;
        lo.x = (_Float16)p[0];   lo.y = (_Float16)p[64];
        hi.x = (_Float16)p[128]; hi.y = (_Float16)p[192];
        o.x = __builtin_bit_cast(unsigned int, lo);
        o.y = __builtin_bit_cast(unsigned int, hi);
        dst[(((size_t)b * Y4_ + y4) * W_ + x0 + x_l) * (size_t)C_ + c0 + c_l] = o;
    }
}

// ---------------------------------------------------------------------------
// k_main: ONE WORKGROUP PER ROI — grid B*N*9 = 1152 (merged the 4 px-chunks
// per ctx roi back into one WG).  R1/R2 showed k_main time is pinned at
// ~85us for ANY 4224-WG variant (~20ns/WG fixed cost: dispatch + prologue),
// insensitive to -28% atomic traffic — so the lever is WG count, not bytes.
// Merging also removes the chunk-overlap duplication in the y-stage (~80K ->
// ~53K inner iterations) and keeps R2's reduced 56.4MB atomic volume (full
// roi = 7 live px = same rows as px-aligned chunks).  Weight-gen, inner
// y4/x-quad dot2 loop, x-stage and epilogue are byte-identical to the
// R0-proven forms.
__global__ __launch_bounds__(256, 4) void k_main(const float* __restrict__ ws_f,
                                                 const float* __restrict__ boxes,
                                                 const float* __restrict__ gt,
                                                 float* __restrict__ outs) {
    __shared__ float        s_wyf[H_][WROW_];      // 1792 B fp32 y staging
    __shared__ unsigned int s_wy2[Y2_ * WROW_];    //  896 B packed half2
    __shared__ float        s_ax[W_][WROW_];       // 1792 B fp32 x-weights

    int bid = blockIdx.x;
    int k   = bid % JR_;                     // 0 = box, 1..8 = ctx union
    int n   = (bid / JR_) & (N_ - 1);
    int b   = bid / (JR_ * N_);
    int tid  = (int)threadIdx.x;
    int c    = tid;

    // ---- roi coords (wave-uniform scalar loads) ----
    const float* bp = boxes + ((size_t)b * N_ + n) * 4;
    float bx1, by1, bx2, by2;
    if (k == 0) {
        bx1 = bp[0]; by1 = bp[1]; bx2 = bp[2]; by2 = bp[3];
    } else {
        const float* gp = gt + ((size_t)b * M_ + (k - 1)) * 4;
        bx1 = fminf(bp[0], gp[0]); by1 = fminf(bp[1], gp[1]);
        bx2 = fmaxf(bp[2], gp[2]); by2 = fmaxf(bp[3], gp[3]);
    }
    float rw = fmaxf(bx2 - bx1, 1.0f);
    float rh = fmaxf(by2 - by1, 1.0f);

    // ---- in-block weight generation (R0 serial column-private form) ----
    for (int e = tid; e < H_ * WROW_; e += 256) ((float*)s_wyf)[e] = 0.0f;
    for (int e = tid; e < W_ * WROW_; e += 256) ((float*)s_ax)[e] = 0.0f;
    __syncthreads();

    if (tid < P_) {                          // y samples, column-private
        int p = tid;
        float bin = rh / 7.0f;
        float gf  = ceilf(bin);
        int   g   = (int)gf;
        float ivg = 1.0f / gf;
        float start = by1 + (float)p * bin;
        for (int ss = 0; ss < g; ++ss) {
            float coord = start + ((float)ss + 0.5f) * bin * ivg;
            if (coord < -1.0f || coord > (float)H_) continue;
            float cc = fmaxf(coord, 0.0f);
            int low = (int)floorf(cc);
            int high; float l;
            if (low >= H_ - 1) { low = H_ - 1; high = H_ - 1; l = 0.0f; }
            else               { high = low + 1; l = cc - (float)low; }
            s_wyf[low][p]  += (1.0f - l) * ivg;
            s_wyf[high][p] += l * ivg;
        }
    } else if (tid >= 64 && tid < 64 + P_) { // x samples, column-private
        int p = tid - 64;
        float bin = rw / 7.0f;
        float gf  = ceilf(bin);
        int   g   = (int)gf;
        float ivg = 1.0f / gf;
        float fs  = (k == 0) ? ivg : ivg * (1.0f / (float)M_);
        float start = bx1 + (float)p * bin;
        for (int ss = 0; ss < g; ++ss) {
            float coord = start + ((float)ss + 0.5f) * bin * ivg;
            if (coord < -1.0f || coord > (float)W_) continue;
            float cc = fmaxf(coord, 0.0f);
            int low = (int)floorf(cc);
            int high; float l;
            if (low >= W_ - 1) { low = W_ - 1; high = W_ - 1; l = 0.0f; }
            else               { high = low + 1; l = cc - (float)low; }
            s_ax[low][p]  += (1.0f - l) * fs;
            s_ax[high][p] += l * fs;
        }
    }
    __syncthreads();

    if (tid < Y2_ * WROW_) {                 // pack y fp32 pairs -> half2
        int q2 = tid >> 3, col = tid & 7;
        half2v h;
        if (col < P_) { h.x = (_Float16)s_wyf[2 * q2][col]; h.y = (_Float16)s_wyf[2 * q2 + 1][col]; }
        else          { h.x = (_Float16)0.0f; h.y = (_Float16)0.0f; }
        s_wy2[tid] = __builtin_bit_cast(unsigned int, h);
    }
    __syncthreads();

    // ---- full-roi column bounds ----
    int xs = min(max((int)floorf(fmaxf(bx1, 0.0f)), 0), W_ - 1);
    int xe = min(max((int)floorf(bx1 + rw) + 1, 0), W_ - 1) + 1;
    int ylo = min(max((int)floorf(fmaxf(by1, 0.0f)), 0), H_ - 1);
    int yhi = min(max((int)floorf(by1 + rh) + 1, 0), H_ - 1) + 1;
    int ylo4 = ylo >> 2;                     // quad range covering [ylo,yhi)
    int yhi4 = (yhi + 3) >> 2;               // extra rows have zero weight

    const uint2* f4 = (const uint2*)ws_f + (size_t)b * (Y4_ * W_ * C_);

    float acc[49];
#pragma unroll
    for (int q = 0; q < 49; ++q) acc[q] = 0.0f;
    int live = 0;

    for (int x = xs; x < xe; x += 4) {
        float cs[4][P_];
#pragma unroll
        for (int i = 0; i < 4; ++i)
#pragma unroll
            for (int py = 0; py < P_; ++py) cs[i][py] = 0.0f;

        // x+1..x+3 over-reads past xe/roi edge stay inside d_ws (spill into
        // the outS region at worst); garbage never enters acc (gated on xe).
        const uint2* cp = f4 + ((size_t)(ylo4 * W_ + x)) * C_ + c;
        for (int y4 = ylo4; y4 < yhi4; ++y4) {
            uint2 d0 = cp[0];
            uint2 d1 = cp[C_];
            uint2 d2 = cp[2 * C_];
            uint2 d3 = cp[3 * C_];
            uint4 wa0 = *(const uint4*)&s_wy2[(2 * y4) * WROW_];
            uint4 wb0 = *(const uint4*)&s_wy2[(2 * y4) * WROW_ + 4];
            uint4 wa1 = *(const uint4*)&s_wy2[(2 * y4 + 1) * WROW_];
            uint4 wb1 = *(const uint4*)&s_wy2[(2 * y4 + 1) * WROW_ + 4];
            half2v w0[7], w1[7];
            w0[0] = __builtin_bit_cast(half2v, wa0.x);
            w0[1] = __builtin_bit_cast(half2v, wa0.y);
            w0[2] = __builtin_bit_cast(half2v, wa0.z);
            w0[3] = __builtin_bit_cast(half2v, wa0.w);
            w0[4] = __builtin_bit_cast(half2v, wb0.x);
            w0[5] = __builtin_bit_cast(half2v, wb0.y);
            w0[6] = __builtin_bit_cast(half2v, wb0.z);
            w1[0] = __builtin_bit_cast(half2v, wa1.x);
            w1[1] = __builtin_bit_cast(half2v, wa1.y);
            w1[2] = __builtin_bit_cast(half2v, wa1.z);
            w1[3] = __builtin_bit_cast(half2v, wa1.w);
            w1[4] = __builtin_bit_cast(half2v, wb1.x);
            w1[5] = __builtin_bit_cast(half2v, wb1.y);
            w1[6] = __builtin_bit_cast(half2v, wb1.z);
            half2v v0a = __builtin_bit_cast(half2v, d0.x);
            half2v v0b = __builtin_bit_cast(half2v, d0.y);
            half2v v1a = __builtin_bit_cast(half2v, d1.x);
            half2v v1b = __builtin_bit_cast(half2v, d1.y);
            half2v v2a = __builtin_bit_cast(half2v, d2.x);
            half2v v2b = __builtin_bit_cast(half2v, d2.y);
            half2v v3a = __builtin_bit_cast(half2v, d3.x);
            half2v v3b = __builtin_bit_cast(half2v, d3.y);
#pragma unroll
            for (int py = 0; py < P_; ++py) {
                cs[0][py] = FDOT2(w1[py], v0b, FDOT2(w0[py], v0a, cs[0][py]));
                cs[1][py] = FDOT2(w1[py], v1b, FDOT2(w0[py], v1a, cs[1][py]));
                cs[2][py] = FDOT2(w1[py], v2b, FDOT2(w0[py], v2a, cs[2][py]));
                cs[3][py] = FDOT2(w1[py], v3b, FDOT2(w0[py], v3a, cs[3][py]));
            }
            cp += W_ * C_;
        }

        // ---- x-stage (fp32, exact weights from LDS) ----
#pragma unroll
        for (int i = 0; i < 4; ++i) {
            if (x + i < xe) {                         // wave-uniform branch
                float av[8];
                *(float4*)(&av[0]) = *(const float4*)&s_ax[x + i][0];
                *(float4*)(&av[4]) = *(const float4*)&s_ax[x + i][4];
#pragma unroll
                for (int px = 0; px < P_; ++px) {
                    float w = av[px];
                    if (w != 0.0f) {
                        live |= 1 << px;
#pragma unroll
                        for (int py = 0; py < P_; ++py)
                            acc[py * P_ + px] = fmaf(w, cs[i][py], acc[py * P_ + px]);
                    }
                }
            }
        }
    }

    // ---- epilogue: live-px coalesced wave-atomics into outS ----
    float* os = outs + ((size_t)b * N_ + n) * (49 * C_) + c;
#pragma unroll
    for (int px = 0; px < P_; ++px) {
        if (live & (1 << px)) {
#pragma unroll
            for (int py = 0; py < P_; ++py)
                atomicAdd(os + (py * P_ + px) * C_, acc[py * P_ + px]);
        }
    }
}

// ---------------------------------------------------------------------------
// k_final: outS [b][n][py][px][c] -> out [b][n][c][py][px] via padded LDS.
// 512 blocks: (bn, 64-channel group) tiles (R1-verified).
__global__ __launch_bounds__(256) void k_final(const float* __restrict__ outs,
                                               float* __restrict__ out) {
    __shared__ float t[49 * 65];             // pad 65: conflict-free transpose
    int bid = blockIdx.x;                    // bn*4 + cg
    int cg  = bid & 3;
    int bn  = bid >> 2;
    int tid = (int)threadIdx.x;
    const float* src = outs + (size_t)bn * (49 * C_) + cg * 64;
    for (int e = tid; e < 49 * 64; e += 256) {
        int q = e >> 6, c = e & 63;
        t[q * 65 + c] = src[q * C_ + c];     // coalesced read
    }
    __syncthreads();
    float* dst = out + (size_t)bn * (C_ * 49) + (size_t)cg * 64 * 49;
    for (int e = tid; e < 64 * 49; e += 256) {
        int c = e / 49, q = e - c * 49;
        dst[e] = t[q * 65 + c];              // coalesced write
    }
}

// ---------------------------------------------------------------------------
extern "C" void kernel_launch(void* const* d_in, const int* in_sizes, int n_in,
                              void* d_out, int out_size, void* d_ws, size_t ws_size,
                              hipStream_t stream) {
    const float* fm    = (const float*)d_in[0];
    const float* boxes = (const float*)d_in[1];
    const float* gt    = (const float*)d_in[2];
    float* ws_f = (float*)d_ws;
    float* out  = (float*)d_out;
    float* outs = ws_f + F_OUTS;

    hipMemsetAsync(outs, 0, (size_t)N_OUTS * sizeof(float), stream);
    k_prep<<<PREP_T, 256, 0, stream>>>(fm, ws_f);
    k_main<<<B_ * N_ * JR_, 256, 0, stream>>>(ws_f, boxes, gt, outs);
    k_final<<<B_ * N_ * 4, 256, 0, stream>>>(outs, out);
}

// Round 4
// 149.374 us; speedup vs baseline: 1.0560x; 1.0560x over previous
//
#include <hip/hip_runtime.h>

#define B_ 2
#define C_ 256
#define H_ 56
#define W_ 56
#define N_ 64
#define M_ 8
#define P_ 7
#define Y2_ (H_/2)               // 28 y-row pairs
#define Y4_ (H_/4)               // 14 y-row quads
#define SCTX_ 4                  // column chunks per ctx roi (box roi = whole)
#define JPN_ (1 + (M_)*SCTX_)    // 33 jobs per (b,n) -> 4224 blocks
#define WROW_ 8                  // padded weight-row stride (7 used + col7 = 0)

typedef _Float16 half2v __attribute__((ext_vector_type(2)));

#if __has_builtin(__builtin_amdgcn_fdot2)
#define FDOT2(a, b, c) __builtin_amdgcn_fdot2((a), (b), (c), false)
#else
static __device__ __forceinline__ float FDOT2(half2v a, half2v b, float c) {
    return fmaf((float)a.x, (float)b.x, fmaf((float)a.y, (float)b.y, c));
}
#endif

// ---- workspace layout (dword-element offsets) ----
#define F_FMT4 0
#define N_FMT4 (B_*Y4_*W_*C_*2)              // 802,816 dw  f16 y-QUAD-packed fmap
#define F_OUTS (F_FMT4 + N_FMT4)
#define N_OUTS (B_*N_*49*C_)                 // 1,605,632 staging out [b][n][py][px][c]
#define WS_ELEMS (F_OUTS + N_OUTS)

// prep kernel block ranges (R2-proven: fused transpose + outS zeroing)
#define PREP_T (B_*Y4_*4*2)                  // 224: (b, y4, cgroup, xhalf) transpose
#define PREP_N (PREP_T + 784)                // + zero outS (784*2048 floats)

// ---------------------------------------------------------------------------
// k_prep (R2-verified): two jobs in one dispatch.
//   [0,224):   COALESCED fm -> fmt4 via LDS tile (112B-run reads, 512B/wave
//              c-contiguous packed stores).
//   [224,1008): zero outS
__global__ __launch_bounds__(256) void k_prep(const float* __restrict__ fm,
                                              float* __restrict__ ws_f) {
    __shared__ float t[28 * 257 + 8];        // [x28][y4][c64], x-stride 257 pad
    int bid = blockIdx.x;
    int tid = (int)threadIdx.x;

    if (bid < PREP_T) {                      // ---- y4 pack-transpose ----
        int xh = bid & 1;
        int cg = (bid >> 1) & 3;
        int y4 = (bid >> 3) % Y4_;
        int b  = (bid >> 3) / Y4_;
        int c0 = cg * 64, x0 = xh * 28;
        for (int e = tid; e < 64 * 4 * 28; e += 256) {
            int c_l = e / 112, rem = e % 112;
            int y_l = rem / 28, x_l = rem % 28;
            t[x_l * 257 + y_l * 64 + c_l] =
                fm[(((size_t)b * C_ + c0 + c_l) * H_ + 4 * y4 + y_l) * W_ + x0 + x_l];
        }
        __syncthreads();
        uint2* dst = (uint2*)ws_f;
        for (int e = tid; e < 28 * 64; e += 256) {
            int x_l = e >> 6, c_l = e & 63;
            const float* p = &t[x_l * 257 + c_l];
            half2v lo, hi; uint2 o;
            lo.x = (_Float16)p[0];   lo.y = (_Float16)p[64];
            hi.x = (_Float16)p[128]; hi.y = (_Float16)p[192];
            o.x = __builtin_bit_cast(unsigned int, lo);
            o.y = __builtin_bit_cast(unsigned int, hi);
            dst[(((size_t)b * Y4_ + y4) * W_ + x0 + x_l) * (size_t)C_ + c0 + c_l] = o;
        }
        return;
    }

    {                                        // ---- zero outS ----
        int tz = (bid - PREP_T) * 256 + tid; // < 200,704
        float4 z = {0.0f, 0.0f, 0.0f, 0.0f};
        float4* dst = (float4*)(ws_f + F_OUTS);
        dst[tz * 2]     = z;
        dst[tz * 2 + 1] = z;
    }
}

// ---------------------------------------------------------------------------
// k_main: block = (b, n, j), grid 4224 — R0's exact structure (fastest
// measured: 81.6us; R1-R3 proved k_main insensitive to WG count, atomic
// volume and iteration count).  SINGLE CHANGE vs R0: the y4 inner loop is
// SOFTWARE-PIPELINED — next iteration's 4 global loads issue before the
// current iteration's FDOT2 block (register rotation d*<-e*).  R0's loop
// serialized [load -> waitcnt(full L2+LDS latency) -> compute] with zero
// cross-iteration MLP; the rotation gives each load a full iteration
// (~300+ cy) to land behind compute, so the counted-vmcnt wait is free.
// Tail prefetch is clamped (reloads current row, L2-hit) -> no OOB.
__global__ __launch_bounds__(256, 4) void k_main(const float* __restrict__ ws_f,
                                                 const float* __restrict__ boxes,
                                                 const float* __restrict__ gt,
                                                 float* __restrict__ outs) {
    __shared__ float        s_wyf[H_][WROW_];      // 1792 B fp32 y staging
    __shared__ unsigned int s_wy2[Y2_ * WROW_];    //  896 B packed half2
    __shared__ float        s_ax[W_][WROW_];       // 1792 B fp32 x-weights

    int bid = blockIdx.x;
    int j   = bid % JPN_;
    int n   = (bid / JPN_) & (N_ - 1);
    int b   = bid / (JPN_ * N_);
    int k, s;
    if (j == 0) { k = 0; s = 0; }
    else        { k = 1 + ((j - 1) >> 2); s = (j - 1) & 3; }
    int tid  = (int)threadIdx.x;
    int c    = tid;

    // ---- roi coords (wave-uniform scalar loads) ----
    const float* bp = boxes + ((size_t)b * N_ + n) * 4;
    float bx1, by1, bx2, by2;
    if (k == 0) {
        bx1 = bp[0]; by1 = bp[1]; bx2 = bp[2]; by2 = bp[3];
    } else {
        const float* gp = gt + ((size_t)b * M_ + (k - 1)) * 4;
        bx1 = fminf(bp[0], gp[0]); by1 = fminf(bp[1], gp[1]);
        bx2 = fmaxf(bp[2], gp[2]); by2 = fmaxf(bp[3], gp[3]);
    }
    float rw = fmaxf(bx2 - bx1, 1.0f);
    float rh = fmaxf(by2 - by1, 1.0f);

    // ---- in-block weight generation (R0 serial column-private form) ----
    for (int e = tid; e < H_ * WROW_; e += 256) ((float*)s_wyf)[e] = 0.0f;
    for (int e = tid; e < W_ * WROW_; e += 256) ((float*)s_ax)[e] = 0.0f;
    __syncthreads();

    if (tid < P_) {                          // y samples, column-private
        int p = tid;
        float bin = rh / 7.0f;
        float gf  = ceilf(bin);
        int   g   = (int)gf;
        float ivg = 1.0f / gf;
        float start = by1 + (float)p * bin;
        for (int ss = 0; ss < g; ++ss) {
            float coord = start + ((float)ss + 0.5f) * bin * ivg;
            if (coord < -1.0f || coord > (float)H_) continue;
            float cc = fmaxf(coord, 0.0f);
            int low = (int)floorf(cc);
            int high; float l;
            if (low >= H_ - 1) { low = H_ - 1; high = H_ - 1; l = 0.0f; }
            else               { high = low + 1; l = cc - (float)low; }
            s_wyf[low][p]  += (1.0f - l) * ivg;
            s_wyf[high][p] += l * ivg;
        }
    } else if (tid >= 64 && tid < 64 + P_) { // x samples, column-private
        int p = tid - 64;
        float bin = rw / 7.0f;
        float gf  = ceilf(bin);
        int   g   = (int)gf;
        float ivg = 1.0f / gf;
        float fs  = (k == 0) ? ivg : ivg * (1.0f / (float)M_);
        float start = bx1 + (float)p * bin;
        for (int ss = 0; ss < g; ++ss) {
            float coord = start + ((float)ss + 0.5f) * bin * ivg;
            if (coord < -1.0f || coord > (float)W_) continue;
            float cc = fmaxf(coord, 0.0f);
            int low = (int)floorf(cc);
            int high; float l;
            if (low >= W_ - 1) { low = W_ - 1; high = W_ - 1; l = 0.0f; }
            else               { high = low + 1; l = cc - (float)low; }
            s_ax[low][p]  += (1.0f - l) * fs;
            s_ax[high][p] += l * fs;
        }
    }
    __syncthreads();

    if (tid < Y2_ * WROW_) {                 // pack y fp32 pairs -> half2
        int q2 = tid >> 3, col = tid & 7;
        half2v h;
        if (col < P_) { h.x = (_Float16)s_wyf[2 * q2][col]; h.y = (_Float16)s_wyf[2 * q2 + 1][col]; }
        else          { h.x = (_Float16)0.0f; h.y = (_Float16)0.0f; }
        s_wy2[tid] = __builtin_bit_cast(unsigned int, h);
    }
    __syncthreads();

    // ---- chunk bounds (uniform per-thread arithmetic, no metadata) ----
    int xlo = min(max((int)floorf(fmaxf(bx1, 0.0f)), 0), W_ - 1);
    int xhi = min(max((int)floorf(bx1 + rw) + 1, 0), W_ - 1) + 1;
    int ylo = min(max((int)floorf(fmaxf(by1, 0.0f)), 0), H_ - 1);
    int yhi = min(max((int)floorf(by1 + rh) + 1, 0), H_ - 1) + 1;
    int xs, xe;
    if (k == 0) { xs = xlo; xe = xhi; }
    else {
        int cw = (xhi - xlo + SCTX_ - 1) >> 2;
        xs = xlo + s * cw;
        xe = min(xs + cw, xhi);
    }
    if (xs >= xe) return;                    // block-uniform, after all barriers

    int ylo4 = ylo >> 2;                     // quad range covering [ylo,yhi)
    int yhi4 = (yhi + 3) >> 2;               // extra rows have zero weight

    const uint2* f4 = (const uint2*)ws_f + (size_t)b * (Y4_ * W_ * C_);

    float acc[49];
#pragma unroll
    for (int q = 0; q < 49; ++q) acc[q] = 0.0f;
    int live = 0;

    for (int x = xs; x < xe; x += 4) {
        float cs[4][P_];
#pragma unroll
        for (int i = 0; i < 4; ++i)
#pragma unroll
            for (int py = 0; py < P_; ++py) cs[i][py] = 0.0f;

        // x+1..x+3 over-reads past xe/roi edge stay inside d_ws (spill into
        // the outS region at worst); garbage never enters acc (gated on xe).
        const uint2* cp = f4 + ((size_t)(ylo4 * W_ + x)) * C_ + c;

        // ---- software-pipelined y4 loop: prefetch rotation d* <- e* ----
        uint2 d0 = cp[0];
        uint2 d1 = cp[C_];
        uint2 d2 = cp[2 * C_];
        uint2 d3 = cp[3 * C_];
        for (int y4 = ylo4; y4 < yhi4; ++y4) {
            // issue NEXT iteration's loads first (clamped at tail: re-loads
            // the current row, an L2 hit whose result is simply unused)
            size_t nstep = (y4 + 1 < yhi4) ? (size_t)(W_ * C_) : 0;
            const uint2* cq = cp + nstep;
            uint2 e0 = cq[0];
            uint2 e1 = cq[C_];
            uint2 e2 = cq[2 * C_];
            uint2 e3 = cq[3 * C_];

            uint4 wa0 = *(const uint4*)&s_wy2[(2 * y4) * WROW_];
            uint4 wb0 = *(const uint4*)&s_wy2[(2 * y4) * WROW_ + 4];
            uint4 wa1 = *(const uint4*)&s_wy2[(2 * y4 + 1) * WROW_];
            uint4 wb1 = *(const uint4*)&s_wy2[(2 * y4 + 1) * WROW_ + 4];
            half2v w0[7], w1[7];
            w0[0] = __builtin_bit_cast(half2v, wa0.x);
            w0[1] = __builtin_bit_cast(half2v, wa0.y);
            w0[2] = __builtin_bit_cast(half2v, wa0.z);
            w0[3] = __builtin_bit_cast(half2v, wa0.w);
            w0[4] = __builtin_bit_cast(half2v, wb0.x);
            w0[5] = __builtin_bit_cast(half2v, wb0.y);
            w0[6] = __builtin_bit_cast(half2v, wb0.z);
            w1[0] = __builtin_bit_cast(half2v, wa1.x);
            w1[1] = __builtin_bit_cast(half2v, wa1.y);
            w1[2] = __builtin_bit_cast(half2v, wa1.z);
            w1[3] = __builtin_bit_cast(half2v, wa1.w);
            w1[4] = __builtin_bit_cast(half2v, wb1.x);
            w1[5] = __builtin_bit_cast(half2v, wb1.y);
            w1[6] = __builtin_bit_cast(half2v, wb1.z);
            half2v v0a = __builtin_bit_cast(half2v, d0.x);
            half2v v0b = __builtin_bit_cast(half2v, d0.y);
            half2v v1a = __builtin_bit_cast(half2v, d1.x);
            half2v v1b = __builtin_bit_cast(half2v, d1.y);
            half2v v2a = __builtin_bit_cast(half2v, d2.x);
            half2v v2b = __builtin_bit_cast(half2v, d2.y);
            half2v v3a = __builtin_bit_cast(half2v, d3.x);
            half2v v3b = __builtin_bit_cast(half2v, d3.y);
#pragma unroll
            for (int py = 0; py < P_; ++py) {
                cs[0][py] = FDOT2(w1[py], v0b, FDOT2(w0[py], v0a, cs[0][py]));
                cs[1][py] = FDOT2(w1[py], v1b, FDOT2(w0[py], v1a, cs[1][py]));
                cs[2][py] = FDOT2(w1[py], v2b, FDOT2(w0[py], v2a, cs[2][py]));
                cs[3][py] = FDOT2(w1[py], v3b, FDOT2(w0[py], v3a, cs[3][py]));
            }
            d0 = e0; d1 = e1; d2 = e2; d3 = e3;
            cp = cq;
        }

        // ---- x-stage (fp32, exact weights from LDS) ----
#pragma unroll
        for (int i = 0; i < 4; ++i) {
            if (x + i < xe) {                         // wave-uniform branch
                float av[8];
                *(float4*)(&av[0]) = *(const float4*)&s_ax[x + i][0];
                *(float4*)(&av[4]) = *(const float4*)&s_ax[x + i][4];
#pragma unroll
                for (int px = 0; px < P_; ++px) {
                    float w = av[px];
                    if (w != 0.0f) {
                        live |= 1 << px;
#pragma unroll
                        for (int py = 0; py < P_; ++py)
                            acc[py * P_ + px] = fmaf(w, cs[i][py], acc[py * P_ + px]);
                    }
                }
            }
        }
    }

    // ---- epilogue: live-px coalesced wave-atomics into outS ----
    float* os = outs + ((size_t)b * N_ + n) * (49 * C_) + c;
#pragma unroll
    for (int px = 0; px < P_; ++px) {
        if (live & (1 << px)) {
#pragma unroll
            for (int py = 0; py < P_; ++py)
                atomicAdd(os + (py * P_ + px) * C_, acc[py * P_ + px]);
        }
    }
}

// ---------------------------------------------------------------------------
// k_final: outS [b][n][py][px][c] -> out [b][n][c][py][px] via padded LDS.
// 512 blocks: (bn, 64-channel group) tiles (R1-verified).
__global__ __launch_bounds__(256) void k_final(const float* __restrict__ outs,
                                               float* __restrict__ out) {
    __shared__ float t[49 * 65];             // pad 65: conflict-free transpose
    int bid = blockIdx.x;                    // bn*4 + cg
    int cg  = bid & 3;
    int bn  = bid >> 2;
    int tid = (int)threadIdx.x;
    const float* src = outs + (size_t)bn * (49 * C_) + cg * 64;
    for (int e = tid; e < 49 * 64; e += 256) {
        int q = e >> 6, c = e & 63;
        t[q * 65 + c] = src[q * C_ + c];     // coalesced read
    }
    __syncthreads();
    float* dst = out + (size_t)bn * (C_ * 49) + (size_t)cg * 64 * 49;
    for (int e = tid; e < 64 * 49; e += 256) {
        int c = e / 49, q = e - c * 49;
        dst[e] = t[q * 65 + c];              // coalesced write
    }
}

// ---------------------------------------------------------------------------
extern "C" void kernel_launch(void* const* d_in, const int* in_sizes, int n_in,
                              void* d_out, int out_size, void* d_ws, size_t ws_size,
                              hipStream_t stream) {
    const float* fm    = (const float*)d_in[0];
    const float* boxes = (const float*)d_in[1];
    const float* gt    = (const float*)d_in[2];
    float* ws_f = (float*)d_ws;
    float* out  = (float*)d_out;
    float* outs = ws_f + F_OUTS;

    k_prep<<<PREP_N, 256, 0, stream>>>(fm, ws_f);
    k_main<<<B_ * N_ * JPN_, 256, 0, stream>>>(ws_f, boxes, gt, outs);
    k_final<<<B_ * N_ * 4, 256, 0, stream>>>(outs, out);
}